// Round 1
// 839.429 us; speedup vs baseline: 1.2896x; 1.2896x over previous
//
#include <hip/hip_runtime.h>
#include <hip/hip_fp16.h>

typedef unsigned int uint;

#define T_DIM 8
#define F_DIM 64
#define BUCKETS 256      // N/BUCKETS = 1024 rows per bucket (N = 262144)
#define RPB 1024         // rows per bucket
#define RPB_SHIFT 10
#define CAP 36864        // per-bucket slot capacity: mean 32768 + 22 sigma
#define SC_BLOCKS 1024   // scatter blocks: chunk = E/1024 = 8192 edges
#define SC_THREADS 512
#define SUB 2048         // edges per sub-chunk (LDS-sorted unit)
#define EPT (SUB / SC_THREADS)  // 4 edges per thread per sub-chunk
#define NSUB 4           // sub-chunks per block

__device__ __forceinline__ uint pack_h2(float a, float b) {
  union { __half2 h2; uint u32; } cvt;
  cvt.h2 = __floats2half2_rn(a, b);
  return cvt.u32;
}
__device__ __forceinline__ float2 unpack_h2(uint v) {
  union { uint u32; __half2 h2; } cvt;
  cvt.u32 = v;
  return __half22float2(cvt.h2);
}

// ---------- fast path ----------

// K1: single-read bin+sort. Per 2048-edge sub-chunk: LDS histogram ->
// LDS scan -> global cursor reservation -> counting-sort records into LDS ->
// coalesced flush (bucket-sorted runs, ~128B contiguous per bucket).
// Records: 16B fp16 payload + 2B local row. idx is read exactly once.
__global__ __launch_bounds__(SC_THREADS) void scatter_sort_kernel(
    const uint* __restrict__ idx, const float* __restrict__ ef,
    uint* __restrict__ cursor, unsigned short* __restrict__ rows_out,
    uint4* __restrict__ recs_out, int E) {
  __shared__ uint hist[BUCKETS];    // pass-1 count, then pass-2 local cursor
  __shared__ uint scan_s[BUCKETS];
  __shared__ uint lbase[BUCKETS];
  __shared__ uint gdelta[BUCKETS];  // bkt*CAP + gbase - lbase  (mod 2^32)
  __shared__ uint srows[SUB];
  __shared__ uint4 srecs[SUB];
  __shared__ int s_is64;
  const int tid = threadIdx.x;
  if (tid == 0) {  // int64 indices have zero high words (values < 2^18)
    uint acc = 0;
    for (int i = 1; i < 64; i += 2) acc |= idx[i];
    s_is64 = (acc == 0);
  }
  __syncthreads();
  const bool is64 = (s_is64 != 0);
  const int cstart = blockIdx.x * (SUB * NSUB);

  for (int sc = 0; sc < NSUB; ++sc) {
    const int base = cstart + sc * SUB;
    if (tid < BUCKETS) hist[tid] = 0;
    __syncthreads();

    // pass 1: read rows (kept in registers), local histogram
    uint r[EPT];
#pragma unroll
    for (int j = 0; j < EPT; ++j) {
      const uint e = base + j * SC_THREADS + tid;
      r[j] = is64 ? idx[(size_t)e << 2] : idx[(size_t)e << 1];
      atomicAdd(&hist[r[j] >> RPB_SHIFT], 1u);
    }
    __syncthreads();

    // exclusive scan of 256 counts (Hillis-Steele, first 256 threads)
    if (tid < BUCKETS) scan_s[tid] = hist[tid];
    __syncthreads();
    for (int off = 1; off < BUCKETS; off <<= 1) {
      uint v = 0;
      if (tid < BUCKETS && tid >= off) v = scan_s[tid - off];
      __syncthreads();
      if (tid < BUCKETS) scan_s[tid] += v;
      __syncthreads();
    }
    if (tid < BUCKETS) {
      const uint cnt = hist[tid];
      const uint lb = scan_s[tid] - cnt;
      lbase[tid] = lb;
      const uint gb = atomicAdd(&cursor[tid], cnt);  // reserve global slots
      gdelta[tid] = (uint)tid * CAP + gb - lb;       // mod-2^32 arithmetic ok
      hist[tid] = 0;                                 // becomes local cursor
    }
    __syncthreads();

    // pass 2: gather ef (coalesced per t), pack fp16, sort into LDS
#pragma unroll
    for (int j = 0; j < EPT; ++j) {
      const uint e = base + j * SC_THREADS + tid;
      const uint row = r[j];
      const uint bkt = row >> RPB_SHIFT;
      const uint p = lbase[bkt] + atomicAdd(&hist[bkt], 1u);
      float v[T_DIM];
#pragma unroll
      for (int t = 0; t < T_DIM; ++t) v[t] = ef[(size_t)t * E + e];
      uint4 rec;
      rec.x = pack_h2(v[0], v[1]);
      rec.y = pack_h2(v[2], v[3]);
      rec.z = pack_h2(v[4], v[5]);
      rec.w = pack_h2(v[6], v[7]);
      srows[p] = row;
      srecs[p] = rec;
    }
    __syncthreads();

    // flush: bucket-sorted LDS -> global, contiguous runs per bucket
#pragma unroll
    for (int j = 0; j < EPT; ++j) {
      const uint i = j * SC_THREADS + tid;
      const uint row = srows[i];
      const uint dst = gdelta[row >> RPB_SHIFT] + i;
      rows_out[dst] = (unsigned short)(row & (RPB - 1));
      recs_out[dst] = srecs[i];
    }
    __syncthreads();
  }
}

// K2: one block per bucket — accumulate fp16 records into padded f32 LDS
// tile (stride 9 breaks stride-8 bank pattern), then fused matmul + bias.
__global__ __launch_bounds__(1024) void accum_mm_kernel(
    const unsigned short* __restrict__ rows, const uint4* __restrict__ recs,
    const uint* __restrict__ cursor, const float* __restrict__ kern,
    const float* __restrict__ bias, float* __restrict__ out) {
  __shared__ float sAgg[RPB * 9];
  __shared__ float sK[T_DIM * F_DIM];
  __shared__ float sB[F_DIM];
  const int tid = threadIdx.x;
  const int b = blockIdx.x;
  for (int i = tid; i < RPB * 9; i += 1024) sAgg[i] = 0.f;
  if (tid < T_DIM * F_DIM / 4) ((float4*)sK)[tid] = ((const float4*)kern)[tid];
  if (tid < F_DIM / 4) ((float4*)sB)[tid] = ((const float4*)bias)[tid];
  __syncthreads();
  const uint cnt = cursor[b];
  const size_t rbase = (size_t)b * CAP;
  for (uint i = tid; i < cnt; i += 1024) {
    const uint r = rows[rbase + i];
    const uint4 rec = recs[rbase + i];
    const float2 f0 = unpack_h2(rec.x);
    const float2 f1 = unpack_h2(rec.y);
    const float2 f2 = unpack_h2(rec.z);
    const float2 f3 = unpack_h2(rec.w);
    float* p = &sAgg[r * 9];
    atomicAdd(p + 0, f0.x);
    atomicAdd(p + 1, f0.y);
    atomicAdd(p + 2, f1.x);
    atomicAdd(p + 3, f1.y);
    atomicAdd(p + 4, f2.x);
    atomicAdd(p + 5, f2.y);
    atomicAdd(p + 6, f3.x);
    atomicAdd(p + 7, f3.y);
  }
  __syncthreads();
  // matmul: RPB rows x 16 float4-chunks of F
  const uint base_row = (uint)b << RPB_SHIFT;
  for (int w = tid; w < RPB * 16; w += 1024) {
    const int rr = w >> 4, q = w & 15;
    const float* a = &sAgg[rr * 9];
    float4 acc = ((const float4*)sB)[q];
#pragma unroll
    for (int t = 0; t < T_DIM; ++t) {
      const float4 kv = ((const float4*)sK)[t * 16 + q];
      const float av = a[t];
      acc.x += av * kv.x;
      acc.y += av * kv.y;
      acc.z += av * kv.z;
      acc.w += av * kv.w;
    }
    *(float4*)(out + (size_t)(base_row + rr) * F_DIM + (q << 2)) = acc;
  }
}

// ---------- fallback path (round-1 atomic version, unchanged) ----------

__global__ __launch_bounds__(256) void scatter_agg_kernel(
    const uint* __restrict__ idx, const float* __restrict__ ef,
    float* __restrict__ agg, int E) {
  __shared__ int s_is64;
  if (threadIdx.x == 0) {
    uint acc = 0;
    for (int i = 1; i < 64; i += 2) acc |= idx[i];
    s_is64 = (acc == 0) ? 1 : 0;
  }
  __syncthreads();
  const bool is64 = (s_is64 != 0);
  const long long base = ((long long)blockIdx.x * blockDim.x + threadIdx.x) * 4;
  if (base >= E) return;
  int rows[4];
  if (is64) {
#pragma unroll
    for (int j = 0; j < 4; ++j) rows[j] = (int)idx[(size_t)(base + j) << 2];
  } else {
#pragma unroll
    for (int j = 0; j < 4; ++j) rows[j] = (int)idx[(size_t)(base + j) << 1];
  }
  float4 v[T_DIM];
#pragma unroll
  for (int t = 0; t < T_DIM; ++t)
    v[t] = *(const float4*)(ef + (size_t)t * E + base);
#pragma unroll
  for (int j = 0; j < 4; ++j) {
    float* dst = agg + (size_t)rows[j] * T_DIM;
#pragma unroll
    for (int t = 0; t < T_DIM; ++t)
      unsafeAtomicAdd(dst + t, ((const float*)&v[t])[j]);
  }
}

__global__ __launch_bounds__(256) void mm_kernel(
    const float* __restrict__ agg, const float* __restrict__ kern,
    const float* __restrict__ bias, float* __restrict__ out, int N) {
  __shared__ float sK[T_DIM * F_DIM];
  __shared__ float sB[F_DIM];
  const int tid = threadIdx.x;
  if (tid < (T_DIM * F_DIM / 4)) ((float4*)sK)[tid] = ((const float4*)kern)[tid];
  if (tid < F_DIM / 4) ((float4*)sB)[tid] = ((const float4*)bias)[tid];
  __syncthreads();
  const long long gid = (long long)blockIdx.x * blockDim.x + tid;
  const int n = (int)(gid >> 4);
  if (n >= N) return;
  const int q = (int)(gid & 15);
  const float4 a0 = *(const float4*)(agg + (size_t)n * T_DIM);
  const float4 a1 = *(const float4*)(agg + (size_t)n * T_DIM + 4);
  const float a[T_DIM] = {a0.x, a0.y, a0.z, a0.w, a1.x, a1.y, a1.z, a1.w};
  float4 r = ((const float4*)sB)[q];
#pragma unroll
  for (int t = 0; t < T_DIM; ++t) {
    const float4 kv = ((const float4*)sK)[t * (F_DIM / 4) + q];
    r.x += a[t] * kv.x;
    r.y += a[t] * kv.y;
    r.z += a[t] * kv.z;
    r.w += a[t] * kv.w;
  }
  *(float4*)(out + (size_t)n * F_DIM + (q << 2)) = r;
}

extern "C" void kernel_launch(void* const* d_in, const int* in_sizes, int n_in,
                              void* d_out, int out_size, void* d_ws,
                              size_t ws_size, hipStream_t stream) {
  const float* ef = (const float*)d_in[0];
  const uint* idx = (const uint*)d_in[1];
  const float* kern = (const float*)d_in[3];
  const float* bias = (const float*)d_in[4];
  float* out = (float*)d_out;

  const int E = in_sizes[1] / 2;   // logical edge count (E,2)
  const int N = out_size / F_DIM;  // 262144

  // workspace carve-out
  size_t off = 0;
  auto carve = [&](size_t bytes) {
    void* p = (char*)d_ws + off;
    off += (bytes + 255) & ~(size_t)255;
    return p;
  };
  uint4* recs = (uint4*)carve((size_t)BUCKETS * CAP * sizeof(uint4));
  unsigned short* rows =
      (unsigned short*)carve((size_t)BUCKETS * CAP * sizeof(unsigned short));
  uint* cursor = (uint*)carve(BUCKETS * sizeof(uint));

  const bool fast = (E == SC_BLOCKS * SUB * NSUB) && (N == BUCKETS * RPB) &&
                    (off <= ws_size);
  if (fast) {
    hipMemsetAsync(cursor, 0, BUCKETS * sizeof(uint), stream);
    scatter_sort_kernel<<<SC_BLOCKS, SC_THREADS, 0, stream>>>(
        idx, ef, cursor, rows, recs, E);
    accum_mm_kernel<<<BUCKETS, 1024, 0, stream>>>(rows, recs, cursor, kern,
                                                  bias, out);
  } else {
    float* agg = (float*)d_ws;  // (N, 8) f32
    hipMemsetAsync(agg, 0, (size_t)N * T_DIM * sizeof(float), stream);
    scatter_agg_kernel<<<(E / 4 + 255) / 256, 256, 0, stream>>>(idx, ef, agg,
                                                                E);
    mm_kernel<<<(int)(((long long)N * 16 + 255) / 256), 256, 0, stream>>>(
        agg, kern, bias, out, N);
  }
}

// Round 2
// 587.566 us; speedup vs baseline: 1.8425x; 1.4287x over previous
//
#include <hip/hip_runtime.h>
#include <hip/hip_fp16.h>

typedef unsigned int uint;

#define T_DIM 8
#define F_DIM 64
#define BUCKETS 256      // N/BUCKETS = 1024 rows per bucket (N = 262144)
#define RPB 1024         // rows per bucket
#define RPB_SHIFT 10
#define CAP 36864        // per-bucket slot capacity: mean 32768 + 22 sigma
#define SC_BLOCKS 1024   // scatter blocks: chunk = E/1024 = 8192 edges
#define SC_THREADS 512
#define SUB 2048         // edges per sub-chunk (LDS-sorted unit)
#define EPT (SUB / SC_THREADS)  // 4 edges per thread per sub-chunk
#define NSUB 4           // sub-chunks per block
#define ACH 3072         // accum chunk records (sorted-LDS unit, 48KB)

__device__ __forceinline__ uint pack_h2(float a, float b) {
  union { __half2 h2; uint u32; } cvt;
  cvt.h2 = __floats2half2_rn(a, b);
  return cvt.u32;
}
__device__ __forceinline__ float2 unpack_h2(uint v) {
  union { uint u32; __half2 h2; } cvt;
  cvt.u32 = v;
  return __half22float2(cvt.h2);
}

// ---------- fast path ----------

// K1: single-read bin+sort. Per 2048-edge sub-chunk: LDS histogram ->
// shfl scan -> global cursor reservation -> counting-sort records into LDS ->
// coalesced flush (bucket-sorted runs). Records: 16B fp16 payload + 2B row.
__global__ __launch_bounds__(SC_THREADS) void scatter_sort_kernel(
    const uint* __restrict__ idx, const float* __restrict__ ef,
    uint* __restrict__ cursor, unsigned short* __restrict__ rows_out,
    uint4* __restrict__ recs_out, int E) {
  __shared__ uint hist[BUCKETS];    // pass-1 count, then pass-2 local cursor
  __shared__ uint lbase[BUCKETS];
  __shared__ uint gdelta[BUCKETS];  // bkt*CAP + gbase - lbase  (mod 2^32)
  __shared__ uint wpart4[4];
  __shared__ uint wpre4[4];
  __shared__ uint srows[SUB];
  __shared__ uint4 srecs[SUB];
  __shared__ int s_is64;
  const int tid = threadIdx.x;
  const int lane = tid & 63;
  const int wid = tid >> 6;
  if (tid == 0) {  // int64 indices have zero high words (values < 2^18)
    uint acc = 0;
    for (int i = 1; i < 64; i += 2) acc |= idx[i];
    s_is64 = (acc == 0);
  }
  __syncthreads();
  const bool is64 = (s_is64 != 0);
  const int cstart = blockIdx.x * (SUB * NSUB);

  for (int sc = 0; sc < NSUB; ++sc) {
    const int base = cstart + sc * SUB;
    if (tid < BUCKETS) hist[tid] = 0;
    __syncthreads();

    // pass 1: read rows (kept in registers), local histogram
    uint r[EPT];
#pragma unroll
    for (int j = 0; j < EPT; ++j) {
      const uint e = base + j * SC_THREADS + tid;
      r[j] = is64 ? idx[(size_t)e << 2] : idx[(size_t)e << 1];
      atomicAdd(&hist[r[j] >> RPB_SHIFT], 1u);
    }
    __syncthreads();

    // shfl-based exclusive scan of 256 counts (waves 0-3)
    uint cntb = 0, x = 0;
    if (tid < BUCKETS) {
      cntb = hist[tid];
      x = cntb;
    }
    for (int o = 1; o < 64; o <<= 1) {
      const uint y = __shfl_up(x, o, 64);
      if (lane >= o) x += y;
    }
    if (tid < BUCKETS && lane == 63) wpart4[wid] = x;
    __syncthreads();
    if (tid == 0) {
      uint run = 0;
#pragma unroll
      for (int w = 0; w < 4; ++w) {
        const uint t = wpart4[w];
        wpre4[w] = run;
        run += t;
      }
    }
    __syncthreads();
    if (tid < BUCKETS) {
      const uint excl = wpre4[wid] + x - cntb;
      lbase[tid] = excl;
      const uint gb = atomicAdd(&cursor[tid], cntb);  // reserve global slots
      gdelta[tid] = (uint)tid * CAP + gb - excl;      // mod-2^32 arithmetic ok
      hist[tid] = 0;                                  // becomes local cursor
    }
    __syncthreads();

    // pass 2: gather ef (coalesced per t), pack fp16, sort into LDS
#pragma unroll
    for (int j = 0; j < EPT; ++j) {
      const uint e = base + j * SC_THREADS + tid;
      const uint row = r[j];
      const uint bkt = row >> RPB_SHIFT;
      const uint p = lbase[bkt] + atomicAdd(&hist[bkt], 1u);
      float v[T_DIM];
#pragma unroll
      for (int t = 0; t < T_DIM; ++t) v[t] = ef[(size_t)t * E + e];
      uint4 rec;
      rec.x = pack_h2(v[0], v[1]);
      rec.y = pack_h2(v[2], v[3]);
      rec.z = pack_h2(v[4], v[5]);
      rec.w = pack_h2(v[6], v[7]);
      srows[p] = row;
      srecs[p] = rec;
    }
    __syncthreads();

    // flush: bucket-sorted LDS -> global, contiguous runs per bucket
#pragma unroll
    for (int j = 0; j < EPT; ++j) {
      const uint i = j * SC_THREADS + tid;
      const uint row = srows[i];
      const uint dst = gdelta[row >> RPB_SHIFT] + i;
      rows_out[dst] = (unsigned short)(row & (RPB - 1));
      recs_out[dst] = srecs[i];
    }
    __syncthreads();
  }
}

// K2: one block per bucket. Per 3072-record chunk: counting-sort by local
// row into LDS (2 atomic incs/record instead of 8 atomic f32 adds), then
// thread r reduces row r's contiguous run into REGISTERS (no atomics).
// Epilogue: registers -> stride-9 LDS tile (aliased over sorted buffer) ->
// fused matmul + bias, coalesced float4 out.
__global__ __launch_bounds__(1024) void accum_mm_kernel(
    const unsigned short* __restrict__ rows, const uint4* __restrict__ recs,
    const uint* __restrict__ cursor, const float* __restrict__ kern,
    const float* __restrict__ bias, float* __restrict__ out) {
  __shared__ uint4 sRec[ACH];       // 48KB sorted records; aliased as sAgg
  __shared__ uint hist[RPB];        // per-row count, then placement cursor
  __shared__ uint wpart[16];
  __shared__ float sK[T_DIM * F_DIM];
  __shared__ float sB[F_DIM];
  const int tid = threadIdx.x;
  const int lane = tid & 63;
  const int wid = tid >> 6;
  const int b = blockIdx.x;
  if (tid < T_DIM * F_DIM / 4) ((float4*)sK)[tid] = ((const float4*)kern)[tid];
  if (tid < F_DIM / 4) ((float4*)sB)[tid] = ((const float4*)bias)[tid];
  const uint cnt = cursor[b];
  const size_t rbase = (size_t)b * CAP;
  float acc[T_DIM];
#pragma unroll
  for (int t = 0; t < T_DIM; ++t) acc[t] = 0.f;

  for (uint c0 = 0; c0 < cnt; c0 += ACH) {
    const uint m = (cnt - c0 < ACH) ? (cnt - c0) : ACH;
    hist[tid] = 0;
    __syncthreads();

    // load rows+recs (registers), histogram over 1024 local rows
    uint rloc[ACH / 1024];
    uint4 rv[ACH / 1024];
#pragma unroll
    for (int j = 0; j < ACH / 1024; ++j) {
      const uint i = (uint)(j * 1024) + tid;
      if (i < m) {
        rloc[j] = rows[rbase + c0 + i];
        rv[j] = recs[rbase + c0 + i];
        atomicAdd(&hist[rloc[j]], 1u);
      }
    }
    __syncthreads();

    // shfl-based exclusive scan of 1024 counts
    const uint mycnt = hist[tid];
    uint x = mycnt;
    for (int o = 1; o < 64; o <<= 1) {
      const uint y = __shfl_up(x, o, 64);
      if (lane >= o) x += y;
    }
    if (lane == 63) wpart[wid] = x;
    __syncthreads();
    if (wid == 0) {
      uint p = (lane < 16) ? wpart[lane] : 0;
      for (int o = 1; o < 16; o <<= 1) {
        const uint y = __shfl_up(p, o, 64);
        if (lane >= o) p += y;
      }
      if (lane < 16) wpart[lane] = p;  // inclusive wave partials
    }
    __syncthreads();
    const uint wbase = (wid == 0) ? 0u : wpart[wid - 1];
    const uint mystart = wbase + x - mycnt;
    hist[tid] = mystart;  // placement cursor
    __syncthreads();

    // place records into row-sorted LDS order
#pragma unroll
    for (int j = 0; j < ACH / 1024; ++j) {
      const uint i = (uint)(j * 1024) + tid;
      if (i < m) {
        const uint p = atomicAdd(&hist[rloc[j]], 1u);
        sRec[p] = rv[j];
      }
    }
    __syncthreads();

    // owner reduce: thread tid sums row tid's run into registers
    for (uint k = 0; k < mycnt; ++k) {
      const uint4 v = sRec[mystart + k];
      const float2 f0 = unpack_h2(v.x);
      const float2 f1 = unpack_h2(v.y);
      const float2 f2 = unpack_h2(v.z);
      const float2 f3 = unpack_h2(v.w);
      acc[0] += f0.x; acc[1] += f0.y;
      acc[2] += f1.x; acc[3] += f1.y;
      acc[4] += f2.x; acc[5] += f2.y;
      acc[6] += f3.x; acc[7] += f3.y;
    }
    __syncthreads();
  }

  // registers -> stride-9 LDS tile (alias over sRec)
  float* sAgg = (float*)sRec;
#pragma unroll
  for (int t = 0; t < T_DIM; ++t) sAgg[tid * 9 + t] = acc[t];
  __syncthreads();

  // matmul: RPB rows x 16 float4-chunks of F
  const uint base_row = (uint)b << RPB_SHIFT;
  for (int w = tid; w < RPB * 16; w += 1024) {
    const int rr = w >> 4, q = w & 15;
    const float* a = &sAgg[rr * 9];
    float4 o4 = ((const float4*)sB)[q];
#pragma unroll
    for (int t = 0; t < T_DIM; ++t) {
      const float4 kv = ((const float4*)sK)[t * 16 + q];
      const float av = a[t];
      o4.x += av * kv.x;
      o4.y += av * kv.y;
      o4.z += av * kv.z;
      o4.w += av * kv.w;
    }
    *(float4*)(out + (size_t)(base_row + rr) * F_DIM + (q << 2)) = o4;
  }
}

// ---------- fallback path (round-1 atomic version, unchanged) ----------

__global__ __launch_bounds__(256) void scatter_agg_kernel(
    const uint* __restrict__ idx, const float* __restrict__ ef,
    float* __restrict__ agg, int E) {
  __shared__ int s_is64;
  if (threadIdx.x == 0) {
    uint acc = 0;
    for (int i = 1; i < 64; i += 2) acc |= idx[i];
    s_is64 = (acc == 0) ? 1 : 0;
  }
  __syncthreads();
  const bool is64 = (s_is64 != 0);
  const long long base = ((long long)blockIdx.x * blockDim.x + threadIdx.x) * 4;
  if (base >= E) return;
  int rows[4];
  if (is64) {
#pragma unroll
    for (int j = 0; j < 4; ++j) rows[j] = (int)idx[(size_t)(base + j) << 2];
  } else {
#pragma unroll
    for (int j = 0; j < 4; ++j) rows[j] = (int)idx[(size_t)(base + j) << 1];
  }
  float4 v[T_DIM];
#pragma unroll
  for (int t = 0; t < T_DIM; ++t)
    v[t] = *(const float4*)(ef + (size_t)t * E + base);
#pragma unroll
  for (int j = 0; j < 4; ++j) {
    float* dst = agg + (size_t)rows[j] * T_DIM;
#pragma unroll
    for (int t = 0; t < T_DIM; ++t)
      unsafeAtomicAdd(dst + t, ((const float*)&v[t])[j]);
  }
}

__global__ __launch_bounds__(256) void mm_kernel(
    const float* __restrict__ agg, const float* __restrict__ kern,
    const float* __restrict__ bias, float* __restrict__ out, int N) {
  __shared__ float sK[T_DIM * F_DIM];
  __shared__ float sB[F_DIM];
  const int tid = threadIdx.x;
  if (tid < (T_DIM * F_DIM / 4)) ((float4*)sK)[tid] = ((const float4*)kern)[tid];
  if (tid < F_DIM / 4) ((float4*)sB)[tid] = ((const float4*)bias)[tid];
  __syncthreads();
  const long long gid = (long long)blockIdx.x * blockDim.x + tid;
  const int n = (int)(gid >> 4);
  if (n >= N) return;
  const int q = (int)(gid & 15);
  const float4 a0 = *(const float4*)(agg + (size_t)n * T_DIM);
  const float4 a1 = *(const float4*)(agg + (size_t)n * T_DIM + 4);
  const float a[T_DIM] = {a0.x, a0.y, a0.z, a0.w, a1.x, a1.y, a1.z, a1.w};
  float4 r = ((const float4*)sB)[q];
#pragma unroll
  for (int t = 0; t < T_DIM; ++t) {
    const float4 kv = ((const float4*)sK)[t * (F_DIM / 4) + q];
    r.x += a[t] * kv.x;
    r.y += a[t] * kv.y;
    r.z += a[t] * kv.z;
    r.w += a[t] * kv.w;
  }
  *(float4*)(out + (size_t)n * F_DIM + (q << 2)) = r;
}

extern "C" void kernel_launch(void* const* d_in, const int* in_sizes, int n_in,
                              void* d_out, int out_size, void* d_ws,
                              size_t ws_size, hipStream_t stream) {
  const float* ef = (const float*)d_in[0];
  const uint* idx = (const uint*)d_in[1];
  const float* kern = (const float*)d_in[3];
  const float* bias = (const float*)d_in[4];
  float* out = (float*)d_out;

  const int E = in_sizes[1] / 2;   // logical edge count (E,2)
  const int N = out_size / F_DIM;  // 262144

  // workspace carve-out
  size_t off = 0;
  auto carve = [&](size_t bytes) {
    void* p = (char*)d_ws + off;
    off += (bytes + 255) & ~(size_t)255;
    return p;
  };
  uint4* recs = (uint4*)carve((size_t)BUCKETS * CAP * sizeof(uint4));
  unsigned short* rows =
      (unsigned short*)carve((size_t)BUCKETS * CAP * sizeof(unsigned short));
  uint* cursor = (uint*)carve(BUCKETS * sizeof(uint));

  const bool fast = (E == SC_BLOCKS * SUB * NSUB) && (N == BUCKETS * RPB) &&
                    (off <= ws_size);
  if (fast) {
    hipMemsetAsync(cursor, 0, BUCKETS * sizeof(uint), stream);
    scatter_sort_kernel<<<SC_BLOCKS, SC_THREADS, 0, stream>>>(
        idx, ef, cursor, rows, recs, E);
    accum_mm_kernel<<<BUCKETS, 1024, 0, stream>>>(rows, recs, cursor, kern,
                                                  bias, out);
  } else {
    float* agg = (float*)d_ws;  // (N, 8) f32
    hipMemsetAsync(agg, 0, (size_t)N * T_DIM * sizeof(float), stream);
    scatter_agg_kernel<<<(E / 4 + 255) / 256, 256, 0, stream>>>(idx, ef, agg,
                                                                E);
    mm_kernel<<<(int)(((long long)N * 16 + 255) / 256), 256, 0, stream>>>(
        agg, kern, bias, out, N);
  }
}